// Round 7
// baseline (41.698 us; speedup 1.0000x reference)
//
#include <hip/hip_runtime.h>

// PlayCell hysteresis scan, single-pass decoupled lookback, RELAXED-only,
// wave-autonomous, fully coalesced.
//   y[t]   = kernel * x[t]
//   out[t] = min(max(out[t-1], y[t]), y[t] + W)   (play operator, W = 1.0)
// Clamp maps compose associatively over (L,H):
//   combine(a then b): L = min(max(La,Lb),Hb), H = min(max(Ha,Lb),Hb).
// Scan value = map applied to initial state: out[t] = min(max(s0, L_t), H_t)
// where (L_t,H_t) is the inclusive composition through t.
//
// Round-6 lesson: per-thread-contiguous chunks made every load/store
// instruction a 64B-stride scatter (16B/lane used) -> request-rate-bound at
// ~3.2 TB/s effective. This version: lane i handles elements [4i,4i+4) of a
// 256-element window -> every float4 load/store is 1 KB contiguous per wave.
// A wave-uniform running prefix U chains 4 windows into a 1024-element unit.
//
// Sync design (round 3/4 lessons): NO acquire/release (agent-scope acquire
// emits per-XCD L2 invalidates -> 5x slowdown). Payloads are single 8-byte
// words; L,H provably finite -> all-ones is an unreachable sentinel; relaxed
// 8B atomic load sees sentinel or complete value. Collapse (aggL==aggH)
// lets units publish INCLUSIVE before lookback -> lookback depth 1.
// No __syncthreads anywhere: stall granularity is one wave, not a block.

#define T_LEN   16777216
#define NTH     256
#define WIN     256                  // elements per window (64 lanes x float4)
#define NWIN    4                    // windows per unit
#define UNIT    (WIN * NWIN)         // 1024 elements per wave-unit
#define NU      (T_LEN / UNIT)       // 16384 units
#define NBLK    (NU / 4)             // 4 wave-units per 256-thread block
#define WPLAY   1.0f

#define SENT    0xFFFFFFFFFFFFFFFFull

__device__ __forceinline__ void combine(float La, float Ha, float Lb, float Hb,
                                        float& Lo, float& Ho) {
    Lo = fminf(fmaxf(La, Lb), Hb);
    Ho = fminf(fmaxf(Ha, Lb), Hb);
}

__device__ __forceinline__ unsigned long long packLH(float L, float H) {
    return ((unsigned long long)__float_as_uint(H) << 32) | (unsigned long long)__float_as_uint(L);
}
__device__ __forceinline__ void unpackLH(unsigned long long u, float& L, float& H) {
    L = __uint_as_float((unsigned)(u & 0xffffffffull));
    H = __uint_as_float((unsigned)(u >> 32));
}

__global__ __launch_bounds__(NTH, 4) void playscan(const float* __restrict__ x,
                                                   const float* __restrict__ kptr,
                                                   const float* __restrict__ s0ptr,
                                                   unsigned long long* __restrict__ payAgg,
                                                   unsigned long long* __restrict__ payInc,
                                                   float* __restrict__ out) {
    const float k  = kptr[0];
    const float s0 = s0ptr[0];
    const int lane = threadIdx.x & 63;
    const int wid  = threadIdx.x >> 6;
    const int unit = blockIdx.x * 4 + wid;
    const long ubase = (long)unit * UNIT;

    // ---- coalesced loads: 1 KB contiguous per wave per instruction ----
    float4 v[NWIN];
#pragma unroll
    for (int w = 0; w < NWIN; ++w)
        v[w] = *(const float4*)(x + ubase + (long)w * WIN + lane * 4);

    // per-element inclusive-from-unit-start maps (kept in registers)
    float rL[NWIN * 4], rH[NWIN * 4];
    float UL = -INFINITY, UH = INFINITY;   // running unit prefix (wave-uniform)

#pragma unroll
    for (int w = 0; w < NWIN; ++w) {
        // per-lane 4-run inclusive pairs
        float pL[4], pH[4];
        float L = -INFINITY, H = INFINITY;
        float y;
        y = k * v[w].x; L = fminf(fmaxf(L, y), y + WPLAY); H = fminf(fmaxf(H, y), y + WPLAY); pL[0] = L; pH[0] = H;
        y = k * v[w].y; L = fminf(fmaxf(L, y), y + WPLAY); H = fminf(fmaxf(H, y), y + WPLAY); pL[1] = L; pH[1] = H;
        y = k * v[w].z; L = fminf(fmaxf(L, y), y + WPLAY); H = fminf(fmaxf(H, y), y + WPLAY); pL[2] = L; pH[2] = H;
        y = k * v[w].w; L = fminf(fmaxf(L, y), y + WPLAY); H = fminf(fmaxf(H, y), y + WPLAY); pL[3] = L; pH[3] = H;

        // ordered wave inclusive scan of lane summaries
#pragma unroll
        for (int d = 1; d < 64; d <<= 1) {
            float Lp = __shfl_up(L, d);
            float Hp = __shfl_up(H, d);
            float Ln, Hn; combine(Lp, Hp, L, H, Ln, Hn);
            if (lane >= d) { L = Ln; H = Hn; }
        }
        // lane-exclusive prefix within window
        float eL = __shfl_up(L, 1), eH = __shfl_up(H, 1);
        if (lane == 0) { eL = -INFINITY; eH = INFINITY; }
        // window aggregate (wave-uniform)
        float AL = __shfl(L, 63), AH = __shfl(H, 63);

        // r_i = p_i ∘ e ∘ U  (apply U, then e, then p_i)
        float ceL, ceH; combine(UL, UH, eL, eH, ceL, ceH);
#pragma unroll
        for (int i = 0; i < 4; ++i)
            combine(ceL, ceH, pL[i], pH[i], rL[w * 4 + i], rH[w * 4 + i]);

        // U = A_w ∘ U
        { float nL, nH; combine(UL, UH, AL, AH, nL, nH); UL = nL; UH = nH; }
    }

    // ---- publish + decoupled lookback (wave-uniform, relaxed only) ----
    const float aggL = UL, aggH = UH;
    float PL = -INFINITY, PH = INFINITY;
    if (unit == 0) {
        if (lane == 0)
            __hip_atomic_store(&payInc[0], packLH(aggL, aggH),
                               __ATOMIC_RELAXED, __HIP_MEMORY_SCOPE_AGENT);
    } else if (aggL == aggH) {
        // collapsed: inclusive == aggregate regardless of prefix
        if (lane == 0)
            __hip_atomic_store(&payInc[unit], packLH(aggL, aggH),
                               __ATOMIC_RELAXED, __HIP_MEMORY_SCOPE_AGENT);
        float accL = -INFINITY, accH = INFINITY;
        int j = unit - 1;
        while (true) {
            unsigned long long ui = __hip_atomic_load(&payInc[j], __ATOMIC_RELAXED,
                                                      __HIP_MEMORY_SCOPE_AGENT);
            if (ui != SENT) {
                float vL, vH; unpackLH(ui, vL, vH);
                combine(vL, vH, accL, accH, PL, PH);
                break;
            }
            unsigned long long ua = __hip_atomic_load(&payAgg[j], __ATOMIC_RELAXED,
                                                      __HIP_MEMORY_SCOPE_AGENT);
            if (ua != SENT) {
                float vL, vH; unpackLH(ua, vL, vH);
                float Ln, Hn; combine(vL, vH, accL, accH, Ln, Hn);
                accL = Ln; accH = Hn;
                if (--j < 0) { PL = accL; PH = accH; break; }
            }
        }
    } else {
        // general path: publish aggregate, lookback, publish inclusive
        if (lane == 0)
            __hip_atomic_store(&payAgg[unit], packLH(aggL, aggH),
                               __ATOMIC_RELAXED, __HIP_MEMORY_SCOPE_AGENT);
        float accL = -INFINITY, accH = INFINITY;
        int j = unit - 1;
        while (true) {
            unsigned long long ui = __hip_atomic_load(&payInc[j], __ATOMIC_RELAXED,
                                                      __HIP_MEMORY_SCOPE_AGENT);
            if (ui != SENT) {
                float vL, vH; unpackLH(ui, vL, vH);
                combine(vL, vH, accL, accH, PL, PH);
                break;
            }
            unsigned long long ua = __hip_atomic_load(&payAgg[j], __ATOMIC_RELAXED,
                                                      __HIP_MEMORY_SCOPE_AGENT);
            if (ua != SENT) {
                float vL, vH; unpackLH(ua, vL, vH);
                float Ln, Hn; combine(vL, vH, accL, accH, Ln, Hn);
                accL = Ln; accH = Hn;
                if (--j < 0) { PL = accL; PH = accH; break; }
            }
        }
        float iL, iH; combine(PL, PH, aggL, aggH, iL, iH);
        if (lane == 0)
            __hip_atomic_store(&payInc[unit], packLH(iL, iH),
                               __ATOMIC_RELAXED, __HIP_MEMORY_SCOPE_AGENT);
    }

    // ---- emit: 2 ops/element, coalesced float4 stores ----
    float s = fminf(fmaxf(s0, PL), PH);   // unit entering state (wave-uniform)
#pragma unroll
    for (int w = 0; w < NWIN; ++w) {
        float4 o;
        o.x = fminf(fmaxf(s, rL[w * 4 + 0]), rH[w * 4 + 0]);
        o.y = fminf(fmaxf(s, rL[w * 4 + 1]), rH[w * 4 + 1]);
        o.z = fminf(fmaxf(s, rL[w * 4 + 2]), rH[w * 4 + 2]);
        o.w = fminf(fmaxf(s, rL[w * 4 + 3]), rH[w * 4 + 3]);
        *(float4*)(out + ubase + (long)w * WIN + lane * 4) = o;
    }
}

extern "C" void kernel_launch(void* const* d_in, const int* in_sizes, int n_in,
                              void* d_out, int out_size, void* d_ws, size_t ws_size,
                              hipStream_t stream) {
    const float* x  = (const float*)d_in[0];   // (T,) float32
    const float* st = (const float*)d_in[1];   // scalar initial state
    const float* kn = (const float*)d_in[2];   // scalar kernel weight
    float* out = (float*)d_out;

    // workspace: payAgg[NU] | payInc[NU], 8B words, sentinel = all-ones
    unsigned long long* payAgg = (unsigned long long*)d_ws;
    unsigned long long* payInc = payAgg + NU;

    // re-arm sentinels every call (ws is not re-poisoned between replays)
    hipMemsetAsync(payAgg, 0xFF, 2 * NU * sizeof(unsigned long long), stream);

    playscan<<<NBLK, NTH, 0, stream>>>(x, kn, st, payAgg, payInc, out);
}

// Round 8
// 36.801 us; speedup vs baseline: 1.1331x; 1.1331x over previous
//
#include <hip/hip_runtime.h>

// PlayCell hysteresis scan — sync-free via halo-collapse, lookback fallback.
//   y[t]   = kernel * x[t]
//   out[t] = min(max(out[t-1], y[t]), y[t] + W)   (play operator, W = 1.0)
// Clamp maps compose associatively over (L,H):
//   combine(a then b): L = min(max(La,Lb),Hb), H = min(max(Ha,Lb),Hb).
// Degenerate-collapse: once a window's composition has L==H=c, composing ANY
// prefix in front yields exactly (c,c); composing more elements after keeps
// it degenerate. So if the 512-element halo before a unit collapses, the
// unit's entering state is c -- exact, with NO cross-unit communication.
// r7 ran in ~40us (not ms) => collapse holds at 1024-elem scale on this data;
// correctness never depends on it (r7's relaxed-sentinel lookback retained
// as the fallback path for non-collapsed halos).
//
// Lessons kept: coalesced wave-window access (r7), relaxed-only atomics
// (r3/r4: acquire/release = per-XCD L2 invalidates, 5x), launch_bounds(256,4)
// (r4: tighter cap spills the register-resident chunk).

#define T_LEN   16777216
#define NTH     256
#define WIN     256                  // elements per window (64 lanes x float4)
#define NWIN    4                    // windows per unit
#define UNIT    (WIN * NWIN)         // 1024 elements per wave-unit
#define NU      (T_LEN / UNIT)       // 16384 units
#define NBLK    (NU / 4)             // 4 wave-units per 256-thread block
#define HALO    512                  // halo elements (2 windows)
#define NHW     (HALO / WIN)         // 2
#define WPLAY   1.0f

#define SENT    0xFFFFFFFFFFFFFFFFull

__device__ __forceinline__ void combine(float La, float Ha, float Lb, float Hb,
                                        float& Lo, float& Ho) {
    Lo = fminf(fmaxf(La, Lb), Hb);
    Ho = fminf(fmaxf(Ha, Lb), Hb);
}

__device__ __forceinline__ unsigned long long packLH(float L, float H) {
    return ((unsigned long long)__float_as_uint(H) << 32) | (unsigned long long)__float_as_uint(L);
}
__device__ __forceinline__ void unpackLH(unsigned long long u, float& L, float& H) {
    L = __uint_as_float((unsigned)(u & 0xffffffffull));
    H = __uint_as_float((unsigned)(u >> 32));
}

__global__ __launch_bounds__(NTH, 4) void playscan(const float* __restrict__ x,
                                                   const float* __restrict__ kptr,
                                                   const float* __restrict__ s0ptr,
                                                   unsigned long long* __restrict__ payAgg,
                                                   unsigned long long* __restrict__ payInc,
                                                   float* __restrict__ out) {
    const float k  = kptr[0];
    const float s0 = s0ptr[0];
    const int lane = threadIdx.x & 63;
    const int wid  = threadIdx.x >> 6;
    const int unit = blockIdx.x * 4 + wid;
    const long ubase = (long)unit * UNIT;

    // ---- coalesced loads: own unit + 512-elem halo before it ----
    float4 v[NWIN];
#pragma unroll
    for (int w = 0; w < NWIN; ++w)
        v[w] = *(const float4*)(x + ubase + (long)w * WIN + lane * 4);

    float4 hv[NHW];
    if (unit > 0) {
#pragma unroll
        for (int w = 0; w < NHW; ++w)
            hv[w] = *(const float4*)(x + ubase - HALO + (long)w * WIN + lane * 4);
    }

    // ---- halo composition Uh (window totals via ordered butterfly) ----
    float UhL = -INFINITY, UhH = INFINITY;
    if (unit > 0) {
#pragma unroll
        for (int w = 0; w < NHW; ++w) {
            float L = -INFINITY, H = INFINITY, y;
            y = k * hv[w].x; L = fminf(fmaxf(L, y), y + WPLAY); H = fminf(fmaxf(H, y), y + WPLAY);
            y = k * hv[w].y; L = fminf(fmaxf(L, y), y + WPLAY); H = fminf(fmaxf(H, y), y + WPLAY);
            y = k * hv[w].z; L = fminf(fmaxf(L, y), y + WPLAY); H = fminf(fmaxf(H, y), y + WPLAY);
            y = k * hv[w].w; L = fminf(fmaxf(L, y), y + WPLAY); H = fminf(fmaxf(H, y), y + WPLAY);
            // ordered butterfly reduce (non-commutative combine; r1-verified)
#pragma unroll
            for (int d = 1; d < 64; d <<= 1) {
                float Lp = __shfl_xor(L, d);
                float Hp = __shfl_xor(H, d);
                float Ln, Hn;
                if (lane & d) combine(Lp, Hp, L, H, Ln, Hn);
                else          combine(L, H, Lp, Hp, Ln, Hn);
                L = Ln; H = Hn;
            }
            float nL, nH; combine(UhL, UhH, L, H, nL, nH); UhL = nL; UhH = nH;
        }
    }

    // ---- own-unit per-element maps relative to unit start (r7 code) ----
    float rL[NWIN * 4], rH[NWIN * 4];
    float UL = -INFINITY, UH = INFINITY;   // own-unit running prefix
#pragma unroll
    for (int w = 0; w < NWIN; ++w) {
        float pL[4], pH[4];
        float L = -INFINITY, H = INFINITY, y;
        y = k * v[w].x; L = fminf(fmaxf(L, y), y + WPLAY); H = fminf(fmaxf(H, y), y + WPLAY); pL[0] = L; pH[0] = H;
        y = k * v[w].y; L = fminf(fmaxf(L, y), y + WPLAY); H = fminf(fmaxf(H, y), y + WPLAY); pL[1] = L; pH[1] = H;
        y = k * v[w].z; L = fminf(fmaxf(L, y), y + WPLAY); H = fminf(fmaxf(H, y), y + WPLAY); pL[2] = L; pH[2] = H;
        y = k * v[w].w; L = fminf(fmaxf(L, y), y + WPLAY); H = fminf(fmaxf(H, y), y + WPLAY); pL[3] = L; pH[3] = H;

#pragma unroll
        for (int d = 1; d < 64; d <<= 1) {
            float Lp = __shfl_up(L, d);
            float Hp = __shfl_up(H, d);
            float Ln, Hn; combine(Lp, Hp, L, H, Ln, Hn);
            if (lane >= d) { L = Ln; H = Hn; }
        }
        float eL = __shfl_up(L, 1), eH = __shfl_up(H, 1);
        if (lane == 0) { eL = -INFINITY; eH = INFINITY; }
        float AL = __shfl(L, 63), AH = __shfl(H, 63);

        float ceL, ceH; combine(UL, UH, eL, eH, ceL, ceH);
#pragma unroll
        for (int i = 0; i < 4; ++i)
            combine(ceL, ceH, pL[i], pH[i], rL[w * 4 + i], rH[w * 4 + i]);

        { float nL, nH; combine(UL, UH, AL, AH, nL, nH); UL = nL; UH = nH; }
    }

    // ---- entering state: collapse fast path / lookback fallback ----
    const float aggL = UL, aggH = UH;    // own-unit aggregate
    float s;
    if (unit == 0) {
        if (lane == 0)
            __hip_atomic_store(&payInc[0], packLH(aggL, aggH),
                               __ATOMIC_RELAXED, __HIP_MEMORY_SCOPE_AGENT);
        s = s0;
    } else if (UhL == UhH) {
        // halo collapsed: entering state is exactly UhL; publish exact INC
        float iL, iH; combine(UhL, UhH, aggL, aggH, iL, iH);
        if (lane == 0)
            __hip_atomic_store(&payInc[unit], packLH(iL, iH),
                               __ATOMIC_RELAXED, __HIP_MEMORY_SCOPE_AGENT);
        s = UhL;
    } else {
        // fallback: r7's relaxed-sentinel decoupled lookback
        if (lane == 0)
            __hip_atomic_store(&payAgg[unit], packLH(aggL, aggH),
                               __ATOMIC_RELAXED, __HIP_MEMORY_SCOPE_AGENT);
        float PL = -INFINITY, PH = INFINITY;
        float accL = -INFINITY, accH = INFINITY;
        int j = unit - 1;
        while (true) {
            unsigned long long ui = __hip_atomic_load(&payInc[j], __ATOMIC_RELAXED,
                                                      __HIP_MEMORY_SCOPE_AGENT);
            if (ui != SENT) {
                float vL, vH; unpackLH(ui, vL, vH);
                combine(vL, vH, accL, accH, PL, PH);
                break;
            }
            unsigned long long ua = __hip_atomic_load(&payAgg[j], __ATOMIC_RELAXED,
                                                      __HIP_MEMORY_SCOPE_AGENT);
            if (ua != SENT) {
                float vL, vH; unpackLH(ua, vL, vH);
                float Ln, Hn; combine(vL, vH, accL, accH, Ln, Hn);
                accL = Ln; accH = Hn;
                if (--j < 0) { PL = accL; PH = accH; break; }
            }
        }
        float iL, iH; combine(PL, PH, aggL, aggH, iL, iH);
        if (lane == 0)
            __hip_atomic_store(&payInc[unit], packLH(iL, iH),
                               __ATOMIC_RELAXED, __HIP_MEMORY_SCOPE_AGENT);
        s = fminf(fmaxf(s0, PL), PH);
    }

    // ---- emit: apply per-element maps to s, coalesced float4 stores ----
#pragma unroll
    for (int w = 0; w < NWIN; ++w) {
        float4 o;
        o.x = fminf(fmaxf(s, rL[w * 4 + 0]), rH[w * 4 + 0]);
        o.y = fminf(fmaxf(s, rL[w * 4 + 1]), rH[w * 4 + 1]);
        o.z = fminf(fmaxf(s, rL[w * 4 + 2]), rH[w * 4 + 2]);
        o.w = fminf(fmaxf(s, rL[w * 4 + 3]), rH[w * 4 + 3]);
        *(float4*)(out + ubase + (long)w * WIN + lane * 4) = o;
    }
}

extern "C" void kernel_launch(void* const* d_in, const int* in_sizes, int n_in,
                              void* d_out, int out_size, void* d_ws, size_t ws_size,
                              hipStream_t stream) {
    const float* x  = (const float*)d_in[0];   // (T,) float32
    const float* st = (const float*)d_in[1];   // scalar initial state
    const float* kn = (const float*)d_in[2];   // scalar kernel weight
    float* out = (float*)d_out;

    // workspace: payAgg[NU] | payInc[NU], 8B words, sentinel = all-ones
    unsigned long long* payAgg = (unsigned long long*)d_ws;
    unsigned long long* payInc = payAgg + NU;

    // re-arm sentinels every call (ws is not re-poisoned between replays);
    // needed only by the rare fallback path, but must stay deterministic.
    hipMemsetAsync(payAgg, 0xFF, 2 * NU * sizeof(unsigned long long), stream);

    playscan<<<NBLK, NTH, 0, stream>>>(x, kn, st, payAgg, payInc, out);
}

// Round 9
// 29.947 us; speedup vs baseline: 1.3924x; 1.2289x over previous
//
#include <hip/hip_runtime.h>

// PlayCell hysteresis scan — fully sync-free via backward collapse walk.
//   y[t]   = kernel * x[t]
//   out[t] = min(max(out[t-1], y[t]), y[t] + W)   (play operator, W = 1.0)
// Clamp maps compose associatively over (L,H):
//   combine(a then b): L = min(max(La,Lb),Hb), H = min(max(Ha,Lb),Hb).
// Degenerate-collapse: once a composition has L==H=c, prepending ANY earlier
// map leaves it exactly (c,c). So each unit walks backward through 256-elem
// windows, prepending window totals until collapse -> entering state = c,
// with NO cross-unit communication. If no collapse by t=0, apply s0 (exact
// for any input; merely slow for adversarial data). r8 proved collapse holds
// within 512 elems on this data (absmax unchanged, -5us).
//
// Lessons kept: coalesced wave-window access (r7); no atomics at all now
// (r3/r4: agent-scope acquire/release = per-XCD L2 invalidates, 5x);
// launch_bounds(256,4) (r4: tighter VGPR cap spills the register chunk);
// single dispatch (r8: small fills cost a ~40us envelope in replay).

#define T_LEN   16777216
#define NTH     256
#define WIN     256                  // elements per window (64 lanes x float4)
#define NWIN    4                    // windows per unit
#define UNIT    (WIN * NWIN)         // 1024 elements per wave-unit
#define NU      (T_LEN / UNIT)       // 16384 units
#define NBLK    (NU / 4)             // 4 wave-units per 256-thread block
#define WPLAY   1.0f

__device__ __forceinline__ void combine(float La, float Ha, float Lb, float Hb,
                                        float& Lo, float& Ho) {
    Lo = fminf(fmaxf(La, Lb), Hb);
    Ho = fminf(fmaxf(Ha, Lb), Hb);
}

__global__ __launch_bounds__(NTH, 4) void playscan(const float* __restrict__ x,
                                                   const float* __restrict__ kptr,
                                                   const float* __restrict__ s0ptr,
                                                   float* __restrict__ out) {
    const float k  = kptr[0];
    const float s0 = s0ptr[0];
    const int lane = threadIdx.x & 63;
    const int wid  = threadIdx.x >> 6;
    const int unit = blockIdx.x * 4 + wid;
    const long ubase = (long)unit * UNIT;

    // ---- coalesced own-unit loads: 1 KB contiguous per wave per instr ----
    float4 v[NWIN];
#pragma unroll
    for (int w = 0; w < NWIN; ++w)
        v[w] = *(const float4*)(x + ubase + (long)w * WIN + lane * 4);

    // ---- own-unit per-element maps relative to unit start ----
    float rL[NWIN * 4], rH[NWIN * 4];
    float UL = -INFINITY, UH = INFINITY;   // running prefix within unit
#pragma unroll
    for (int w = 0; w < NWIN; ++w) {
        float pL[4], pH[4];
        float L = -INFINITY, H = INFINITY, y;
        y = k * v[w].x; L = fminf(fmaxf(L, y), y + WPLAY); H = fminf(fmaxf(H, y), y + WPLAY); pL[0] = L; pH[0] = H;
        y = k * v[w].y; L = fminf(fmaxf(L, y), y + WPLAY); H = fminf(fmaxf(H, y), y + WPLAY); pL[1] = L; pH[1] = H;
        y = k * v[w].z; L = fminf(fmaxf(L, y), y + WPLAY); H = fminf(fmaxf(H, y), y + WPLAY); pL[2] = L; pH[2] = H;
        y = k * v[w].w; L = fminf(fmaxf(L, y), y + WPLAY); H = fminf(fmaxf(H, y), y + WPLAY); pL[3] = L; pH[3] = H;

        // ordered wave inclusive scan of lane summaries
#pragma unroll
        for (int d = 1; d < 64; d <<= 1) {
            float Lp = __shfl_up(L, d);
            float Hp = __shfl_up(H, d);
            float Ln, Hn; combine(Lp, Hp, L, H, Ln, Hn);
            if (lane >= d) { L = Ln; H = Hn; }
        }
        float eL = __shfl_up(L, 1), eH = __shfl_up(H, 1);
        if (lane == 0) { eL = -INFINITY; eH = INFINITY; }
        float AL = __shfl(L, 63), AH = __shfl(H, 63);

        float ceL, ceH; combine(UL, UH, eL, eH, ceL, ceH);
#pragma unroll
        for (int i = 0; i < 4; ++i)
            combine(ceL, ceH, pL[i], pH[i], rL[w * 4 + i], rH[w * 4 + i]);

        { float nL, nH; combine(UL, UH, AL, AH, nL, nH); UL = nL; UH = nH; }
    }

    // ---- entering state: backward collapse walk (wave-uniform) ----
    float s;
    if (unit == 0) {
        s = s0;
    } else {
        float accL = -INFINITY, accH = INFINITY;   // suffix [j..unit*NWIN-1]
        long j = (long)unit * NWIN - 1;            // global window index
        while (true) {
            // window-j total: coalesced load + ordered butterfly reduce
            const float* wp = x + j * WIN;
            float4 hv = *(const float4*)(wp + lane * 4);
            float L = -INFINITY, H = INFINITY, y;
            y = k * hv.x; L = fminf(fmaxf(L, y), y + WPLAY); H = fminf(fmaxf(H, y), y + WPLAY);
            y = k * hv.y; L = fminf(fmaxf(L, y), y + WPLAY); H = fminf(fmaxf(H, y), y + WPLAY);
            y = k * hv.z; L = fminf(fmaxf(L, y), y + WPLAY); H = fminf(fmaxf(H, y), y + WPLAY);
            y = k * hv.w; L = fminf(fmaxf(L, y), y + WPLAY); H = fminf(fmaxf(H, y), y + WPLAY);
#pragma unroll
            for (int d = 1; d < 64; d <<= 1) {
                float Lp = __shfl_xor(L, d);
                float Hp = __shfl_xor(H, d);
                float Ln, Hn;
                if (lane & d) combine(Lp, Hp, L, H, Ln, Hn);
                else          combine(L, H, Lp, Hp, Ln, Hn);
                L = Ln; H = Hn;
            }
            // prepend: acc = A_j then acc
            { float nL, nH; combine(L, H, accL, accH, nL, nH); accL = nL; accH = nH; }
            if (accL == accH) { s = accL; break; }          // collapsed: exact
            if (--j < 0) { s = fminf(fmaxf(s0, accL), accH); break; }
        }
    }

    // ---- emit: apply per-element maps to s, coalesced float4 stores ----
#pragma unroll
    for (int w = 0; w < NWIN; ++w) {
        float4 o;
        o.x = fminf(fmaxf(s, rL[w * 4 + 0]), rH[w * 4 + 0]);
        o.y = fminf(fmaxf(s, rL[w * 4 + 1]), rH[w * 4 + 1]);
        o.z = fminf(fmaxf(s, rL[w * 4 + 2]), rH[w * 4 + 2]);
        o.w = fminf(fmaxf(s, rL[w * 4 + 3]), rH[w * 4 + 3]);
        *(float4*)(out + ubase + (long)w * WIN + lane * 4) = o;
    }
}

extern "C" void kernel_launch(void* const* d_in, const int* in_sizes, int n_in,
                              void* d_out, int out_size, void* d_ws, size_t ws_size,
                              hipStream_t stream) {
    const float* x  = (const float*)d_in[0];   // (T,) float32
    const float* st = (const float*)d_in[1];   // scalar initial state
    const float* kn = (const float*)d_in[2];   // scalar kernel weight
    float* out = (float*)d_out;

    playscan<<<NBLK, NTH, 0, stream>>>(x, kn, st, out);
}

// Round 10
// 29.396 us; speedup vs baseline: 1.4185x; 1.0188x over previous
//
#include <hip/hip_runtime.h>

// PlayCell hysteresis scan — sync-free backward collapse walk, block-shared.
//   y[t]   = kernel * x[t]
//   out[t] = min(max(out[t-1], y[t]), y[t] + W)   (play operator, W = 1.0)
// Clamp maps compose associatively over (L,H):
//   combine(a then b): L = min(max(La,Lb),Hb), H = min(max(Ha,Lb),Hb).
// Degenerate-collapse: once a composition has L==H=c, prepending ANY earlier
// map leaves it exactly (c,c). Wave 0 of each block walks backward through
// 256-elem windows until collapse -> block entering STATE, exact, no
// cross-block communication (falls back to s0 at t=0 for any data). Waves
// 1..3 chain from it via in-block LDS aggregates (r10: cuts halo re-reads
// 4x vs per-wave walks). Out-stores are nontemporal: out is never re-read,
// keep L2 for the x halo windows.
//
// Lessons kept: coalesced wave-window access (r7); no atomics (r3/r4:
// agent-scope acquire/release = per-XCD L2 invalidates, 5x); single dispatch
// (r8: every extra small dispatch costs a ~40us envelope in replay);
// launch_bounds(256,4) (r4: tighter VGPR cap spills the register chunk).

#define T_LEN   16777216
#define NTH     256
#define WIN     256                  // elements per window (64 lanes x float4)
#define NWIN    4                    // windows per unit
#define UNIT    (WIN * NWIN)         // 1024 elements per wave-unit
#define NU      (T_LEN / UNIT)       // 16384 units
#define NBLK    (NU / 4)             // 4096 blocks, 4 wave-units each
#define BWINS   (4 * NWIN)           // 16 windows per block
#define WPLAY   1.0f

typedef float f32x4 __attribute__((ext_vector_type(4)));

__device__ __forceinline__ void combine(float La, float Ha, float Lb, float Hb,
                                        float& Lo, float& Ho) {
    Lo = fminf(fmaxf(La, Lb), Hb);
    Ho = fminf(fmaxf(Ha, Lb), Hb);
}

__global__ __launch_bounds__(NTH, 4) void playscan(const float* __restrict__ x,
                                                   const float* __restrict__ kptr,
                                                   const float* __restrict__ s0ptr,
                                                   float* __restrict__ out) {
    const float k  = kptr[0];
    const float s0 = s0ptr[0];
    const int lane = threadIdx.x & 63;
    const int wid  = threadIdx.x >> 6;
    const int unit = blockIdx.x * 4 + wid;
    const long ubase = (long)unit * UNIT;

    const bool walker = (wid == 0) && (blockIdx.x > 0);
    long j = (long)blockIdx.x * BWINS - 1;   // window just before this block

    // issue walk-window load EARLY so it resolves under the own-unit scan
    float4 hv;
    if (walker) hv = *(const float4*)(x + j * WIN + lane * 4);

    // ---- coalesced own-unit loads: 1 KB contiguous per wave per instr ----
    float4 v[NWIN];
#pragma unroll
    for (int w = 0; w < NWIN; ++w)
        v[w] = *(const float4*)(x + ubase + (long)w * WIN + lane * 4);

    // ---- own-unit per-element maps relative to unit start ----
    float rL[NWIN * 4], rH[NWIN * 4];
    float UL = -INFINITY, UH = INFINITY;   // running prefix within unit
#pragma unroll
    for (int w = 0; w < NWIN; ++w) {
        float pL[4], pH[4];
        float L = -INFINITY, H = INFINITY, y;
        y = k * v[w].x; L = fminf(fmaxf(L, y), y + WPLAY); H = fminf(fmaxf(H, y), y + WPLAY); pL[0] = L; pH[0] = H;
        y = k * v[w].y; L = fminf(fmaxf(L, y), y + WPLAY); H = fminf(fmaxf(H, y), y + WPLAY); pL[1] = L; pH[1] = H;
        y = k * v[w].z; L = fminf(fmaxf(L, y), y + WPLAY); H = fminf(fmaxf(H, y), y + WPLAY); pL[2] = L; pH[2] = H;
        y = k * v[w].w; L = fminf(fmaxf(L, y), y + WPLAY); H = fminf(fmaxf(H, y), y + WPLAY); pL[3] = L; pH[3] = H;

        // ordered wave inclusive scan of lane summaries
#pragma unroll
        for (int d = 1; d < 64; d <<= 1) {
            float Lp = __shfl_up(L, d);
            float Hp = __shfl_up(H, d);
            float Ln, Hn; combine(Lp, Hp, L, H, Ln, Hn);
            if (lane >= d) { L = Ln; H = Hn; }
        }
        float eL = __shfl_up(L, 1), eH = __shfl_up(H, 1);
        if (lane == 0) { eL = -INFINITY; eH = INFINITY; }
        float AL = __shfl(L, 63), AH = __shfl(H, 63);

        float ceL, ceH; combine(UL, UH, eL, eH, ceL, ceH);
#pragma unroll
        for (int i = 0; i < 4; ++i)
            combine(ceL, ceH, pL[i], pH[i], rL[w * 4 + i], rH[w * 4 + i]);

        { float nL, nH; combine(UL, UH, AL, AH, nL, nH); UL = nL; UH = nH; }
    }

    // ---- post unit aggregates; wave 0 walks; share entering state ----
    __shared__ float aL[4], aH[4];
    __shared__ float sBs;
    if (lane == 0) { aL[wid] = UL; aH[wid] = UH; }
    __syncthreads();

    if (wid == 0) {
        float sB;
        if (blockIdx.x == 0) {
            sB = s0;
        } else {
            float accL = -INFINITY, accH = INFINITY;  // map of windows (j..B-1]
            while (true) {
                // reduce current walk window (ordered butterfly)
                float L = -INFINITY, H = INFINITY, y;
                y = k * hv.x; L = fminf(fmaxf(L, y), y + WPLAY); H = fminf(fmaxf(H, y), y + WPLAY);
                y = k * hv.y; L = fminf(fmaxf(L, y), y + WPLAY); H = fminf(fmaxf(H, y), y + WPLAY);
                y = k * hv.z; L = fminf(fmaxf(L, y), y + WPLAY); H = fminf(fmaxf(H, y), y + WPLAY);
                y = k * hv.w; L = fminf(fmaxf(L, y), y + WPLAY); H = fminf(fmaxf(H, y), y + WPLAY);
#pragma unroll
                for (int d = 1; d < 64; d <<= 1) {
                    float Lp = __shfl_xor(L, d);
                    float Hp = __shfl_xor(H, d);
                    float Ln, Hn;
                    if (lane & d) combine(Lp, Hp, L, H, Ln, Hn);
                    else          combine(L, H, Lp, Hp, Ln, Hn);
                    L = Ln; H = Hn;
                }
                // prepend: acc = A_j then acc
                { float nL, nH; combine(L, H, accL, accH, nL, nH); accL = nL; accH = nH; }
                if (accL == accH) { sB = accL; break; }          // collapsed
                if (--j < 0)      { sB = fminf(fmaxf(s0, accL), accH); break; }
                hv = *(const float4*)(x + j * WIN + lane * 4);   // next window
            }
        }
        if (lane == 0) sBs = sB;
    }
    __syncthreads();

    // entering state for this wave: block state chained through waves 0..wid-1
    float s = sBs;
    for (int w = 0; w < wid; ++w) s = fminf(fmaxf(s, aL[w]), aH[w]);

    // ---- emit: apply per-element maps, nontemporal coalesced stores ----
#pragma unroll
    for (int w = 0; w < NWIN; ++w) {
        f32x4 o;
        o.x = fminf(fmaxf(s, rL[w * 4 + 0]), rH[w * 4 + 0]);
        o.y = fminf(fmaxf(s, rL[w * 4 + 1]), rH[w * 4 + 1]);
        o.z = fminf(fmaxf(s, rL[w * 4 + 2]), rH[w * 4 + 2]);
        o.w = fminf(fmaxf(s, rL[w * 4 + 3]), rH[w * 4 + 3]);
        __builtin_nontemporal_store(o, (f32x4*)(out + ubase + (long)w * WIN + lane * 4));
    }
}

extern "C" void kernel_launch(void* const* d_in, const int* in_sizes, int n_in,
                              void* d_out, int out_size, void* d_ws, size_t ws_size,
                              hipStream_t stream) {
    const float* x  = (const float*)d_in[0];   // (T,) float32
    const float* st = (const float*)d_in[1];   // scalar initial state
    const float* kn = (const float*)d_in[2];   // scalar kernel weight
    float* out = (float*)d_out;

    playscan<<<NBLK, NTH, 0, stream>>>(x, kn, st, out);
}